// Round 9
// baseline (228.028 us; speedup 1.0000x reference)
//
#include <hip/hip_runtime.h>

typedef unsigned short u16;
typedef unsigned int u32;
typedef short bf16x8 __attribute__((ext_vector_type(8)));
typedef float f32x4 __attribute__((ext_vector_type(4)));
typedef u32 u32x4 __attribute__((ext_vector_type(4)));

#define AS_GLOBAL __attribute__((address_space(1)))
#define AS_LDS __attribute__((address_space(3)))

__device__ __forceinline__ void async16(const void* g, void* l) {
  __builtin_amdgcn_global_load_lds((const AS_GLOBAL u32*)g, (AS_LDS u32*)l, 16, 0, 0);
}

__device__ __forceinline__ u16 f2bf(float f) {
  u32 u = __builtin_bit_cast(u32, f);
  u += 0x7FFFu + ((u >> 16) & 1u);   // RNE
  return (u16)(u >> 16);
}

__device__ __forceinline__ u32 pk2bf(float lo, float hi) {
  return __builtin_amdgcn_perm(__builtin_bit_cast(u32, hi),
                               __builtin_bit_cast(u32, lo), 0x07060302u);
}

__device__ __forceinline__ float fexp2(float x) {
#if __has_builtin(__builtin_amdgcn_exp2f)
  return __builtin_amdgcn_exp2f(x);
#else
  return exp2f(x);
#endif
}

// ---------------- Pass A: all four f32 -> bf16 converts in one launch ----------------
__global__ __launch_bounds__(256) void cvt_all(const float* __restrict__ x,
                                               const float* __restrict__ wq,
                                               const float* __restrict__ wk,
                                               const float* __restrict__ wv,
                                               u16* __restrict__ xb,
                                               u16* __restrict__ wb) {
  const int blk = blockIdx.x;
  const float* src;
  u16* dst;
  int i;
  if (blk < 8192) {
    src = x; dst = xb; i = blk * 256 + threadIdx.x;
  } else if (blk < 9216) {
    src = wq; dst = wb; i = (blk - 8192) * 256 + threadIdx.x;
  } else if (blk < 10240) {
    src = wk; dst = wb + 1048576; i = (blk - 9216) * 256 + threadIdx.x;
  } else {
    src = wv; dst = wb + 2097152; i = (blk - 10240) * 256 + threadIdx.x;
  }
  float4 f = reinterpret_cast<const float4*>(src)[i];
  ushort4 o;
  o.x = f2bf(f.x); o.y = f2bf(f.y); o.z = f2bf(f.z); o.w = f2bf(f.w);
  reinterpret_cast<ushort4*>(dst)[i] = o;
}

// ---------------- Pass B: QKV projection GEMM (C = X * W^T) ----------------
// ROUND-7 PROVEN VERSION, UNCHANGED (wide-store epilogue win: 88 -> ~60 us).
// K-loop: 256 thr, 2x2 waves of 64x64, BK=64, double-buffered LDS, one
// __syncthreads per k-tile, conflict-free chunk-XOR swizzle. Epilogue stages
// C through LDS and emits 8 x global_store_dwordx4 per thread.
// grid: x = m-tile (64), y = n-tile (8), z = matrix (3)
// z=0 (Q), z=1 (K): out [B][H][T][64]; z=2 (V): out TRANSPOSED [B][H][64][T]
__global__ __launch_bounds__(256, 2) void qkv_gemm(const u16* __restrict__ X,
                                                   const u16* __restrict__ W,
                                                   u16* __restrict__ O) {
  const int z = blockIdx.z;
  const u16* Wz = W + (size_t)z * (1024 * 1024);
  u16* Oz = O + (size_t)z * (8192 * 1024);

  // unified 64KB: SMEM[0..1] = A dbuf, SMEM[2..3] = B dbuf; epilogue reuses
  // SMEM[w] as wave-private staging (8192 u16 each >= 64*80).
  __shared__ __align__(16) u16 SMEM[4][8192];

  const int t = threadIdx.x;
  const int lane = t & 63, w = t >> 6, quad = lane >> 4, lq = lane & 15;
  const int wm = (w >> 1) * 64, wn = (w & 1) * 64;
  const int sw = lq & 7;
  const size_t m0 = (size_t)blockIdx.x * 128;
  const int n0 = blockIdx.y * 128;

  // staging source offsets (u16 units): slot -> (row, pre-swizzled chunk)
  int off[4];
#pragma unroll
  for (int j = 0; j < 4; ++j) {
    const int s = j * 256 + t, row = s >> 3, c = (s & 7) ^ (row & 7);
    off[j] = row * 1024 + c * 8;
  }
  const u16* gA = X + m0 * 1024;
  const u16* gB = Wz + (size_t)n0 * 1024;

  f32x4 acc[4][4];
#pragma unroll
  for (int i = 0; i < 4; ++i)
#pragma unroll
    for (int j = 0; j < 4; ++j) acc[i][j] = f32x4{0.f, 0.f, 0.f, 0.f};

  // 8 gload_lds(16B)/thread stages one 128x64 A panel + 128x64 B panel
  auto stage = [&](int kt, int nb) {
    const u16* ga = gA + kt * 64;
    const u16* gb = gB + kt * 64;
#pragma unroll
    for (int j = 0; j < 4; ++j)
      async16(ga + off[j], &SMEM[nb][(j * 256 + t) * 8]);
#pragma unroll
    for (int j = 0; j < 4; ++j)
      async16(gb + off[j], &SMEM[2 + nb][(j * 256 + t) * 8]);
  };

  // prologue: stage tile 0 into buffer 0
  stage(0, 0);

  for (int kt = 0; kt < 16; ++kt) {
    const int cur = kt & 1;
    __syncthreads();                    // tile kt resident; buf[cur^1] free
    if (kt < 15) stage(kt + 1, cur ^ 1);

    bf16x8 Af[4][2], Bf[4][2];
#pragma unroll
    for (int i = 0; i < 4; ++i)
#pragma unroll
      for (int ks = 0; ks < 2; ++ks) {
        Af[i][ks] = *reinterpret_cast<const bf16x8*>(
            &SMEM[cur][(wm + i * 16 + lq) * 64 + ((ks * 4 + quad) ^ sw) * 8]);
        Bf[i][ks] = *reinterpret_cast<const bf16x8*>(
            &SMEM[2 + cur][(wn + i * 16 + lq) * 64 + ((ks * 4 + quad) ^ sw) * 8]);
      }
#pragma unroll
    for (int i = 0; i < 4; ++i)
#pragma unroll
      for (int j = 0; j < 4; ++j) {
        acc[i][j] = __builtin_amdgcn_mfma_f32_16x16x32_bf16(Af[i][0], Bf[j][0], acc[i][j], 0, 0, 0);
        acc[i][j] = __builtin_amdgcn_mfma_f32_16x16x32_bf16(Af[i][1], Bf[j][1], acc[i][j], 0, 0, 0);
      }
  }

  // ---- wide-store epilogue ----
  __syncthreads();                      // all LDS reads of the main loop done
  u16* ep = &SMEM[w][0];                // wave-private region, layout [64][80]
  if (z != 2) {
    // LDS row = local m (0..63), col = local n (0..63)
#pragma unroll
    for (int i = 0; i < 4; ++i)
#pragma unroll
      for (int j = 0; j < 4; ++j)
#pragma unroll
        for (int r = 0; r < 4; ++r)
          ep[(i * 16 + quad * 4 + r) * 80 + j * 16 + lq] = f2bf(acc[i][j][r]);
  } else {
    // transposed: LDS row = local n (=d), col = local m (=t)
#pragma unroll
    for (int i = 0; i < 4; ++i)
#pragma unroll
      for (int j = 0; j < 4; ++j)
#pragma unroll
        for (int r = 0; r < 4; ++r)
          ep[(j * 16 + lq) * 80 + i * 16 + quad * 4 + r] = f2bf(acc[i][j][r]);
  }
  asm volatile("s_waitcnt lgkmcnt(0)" ::: "memory");  // own-wave writes visible

  const int r8 = lane >> 3, c8 = lane & 7;            // 8 rows x 8 chunks
  const size_t ms = m0 + wm;
  const size_t bb = ms >> 11, tt0 = ms & 2047;
  const int hh = (n0 + wn) >> 6;
  if (z != 2) {
    // wave tile = contiguous 8KB at ((bb*16+hh)*2048 + tt0)*64
    u16* gbase = Oz + ((bb * 16 + hh) * 2048 + tt0) * 64;
#pragma unroll
    for (int kq = 0; kq < 8; ++kq) {
      const int row = kq * 8 + r8;
      bf16x8 v = *reinterpret_cast<const bf16x8*>(&ep[row * 80 + c8 * 8]);
      *reinterpret_cast<bf16x8*>(&gbase[(size_t)row * 64 + c8 * 8]) = v;
    }
  } else {
    // wave tile = 64 rows (d) of 128B at stride 4KB
    u16* gbase = Oz + ((size_t)(bb * 16 + hh) * 64) * 2048 + tt0;
#pragma unroll
    for (int kq = 0; kq < 8; ++kq) {
      const int row = kq * 8 + r8;
      bf16x8 v = *reinterpret_cast<const bf16x8*>(&ep[row * 80 + c8 * 8]);
      *reinterpret_cast<bf16x8*>(&gbase[(size_t)row * 2048 + c8 * 8]) = v;
    }
  }
}

// ---------------- Pass C: flash attention, S^T-form, full-rate 16x16x32 PV ----------------
// Round-9 experiment: q-tile split 8 -> 16 (128 q/block, 8 waves x 16 q/wave,
// qg loop ELIMINATED). Grid 64 x 16 = 1024 blocks -> 4 blocks/CU -> 32
// waves/CU (launch_bounds(512,8); per-wave state ~55 VGPR fits the 64-VGPR
// 8-wave budget). Per-CU MFMA/exp/LDS work unchanged (K/V LDS shared per
// block); K/V HBM fetch doubles (~26 -> ~40 MB, trivial at 9% BW). Pure
// pipe-overlap lever: r8 showed MfmaUtil 44 + VALUBusy 51 = 95% with the
// serial QK->exp->PV chain -- more resident waves interleave the pipes.
//
// Key-permuted S^T (unchanged): for 32-key half `half`, sub-MFMA kg2 reads
// K row key(m) = half*32 + (m>>2)*8 + kg2*4 + (m&3), so each lane's 8 P
// values sit at keys quad*8+{0..7} == the 16x16x32 A-frag layout. PV at full
// 2xK rate; V B-frag one contiguous bf16x8 per dg. Row-sum via
// mfma(pa, ones, Lacc). Palace mask: q = qt*128 + w*16 + lq ->
// q-slot = (w&3)*2 + lq3 (qt*128 == 0 mod 64); key-slot = half*4 + quad.
// LDS swizzle: position = chunk ^ s(row), s(row) = (row&3) | (((row>>3)&1)<<2).
__global__ __launch_bounds__(512, 8) void palace_attn(const u16* __restrict__ Q,
                                                      const u16* __restrict__ K,
                                                      const u16* __restrict__ Vt,
                                                      float* __restrict__ out,
                                                      const float* __restrict__ wptr) {
  const int bh = blockIdx.x, qt = blockIdx.y;
  const int h = bh & 15, b = bh >> 4;
  const size_t base = (size_t)bh * (2048 * 64);

  __shared__ __align__(16) u16 Ks[2][64 * 64];   // [key][d], swizzled 16B chunks
  __shared__ __align__(16) u16 Vs[2][64 * 64];   // [d][key], swizzled 16B chunks

  const int t = threadIdx.x;
  const int w = t >> 6, lane = t & 63, quad = lane >> 4, lq = lane & 15;
  const int lq3 = lq >> 3;
  const int swk = (lq & 3) | (((lq >> 2) & 1) << 2);  // s(row) for permuted K rows
  const int swv = (lq & 3) | (lq3 << 2);              // s(d) for V rows d=dg*16+lq
  const float sig = 1.f / (1.f + __expf(-wptr[0]));
  const float Ci = 0.125f * 1.44269504f;   // intra coeff (scale * log2 e)
  const float Co = Ci * sig;               // inter coeff
  const float MC = 14.4269504f;            // fixed softmax offset: 10 * log2 e

  // palace mask: q-slot = (w&3)*2 + lq3; key-slot = half*4 + quad
  const int qs = (w & 3) * 2 + lq3;
  float cft[2];
#pragma unroll
  for (int half = 0; half < 2; ++half)
    cft[half] = (half * 4 + quad == qs) ? Ci : Co;

  // Q B-frags (16x16x32): B[k=d][n=q], q = qt*128 + w*16 + lq
  bf16x8 qf[2];
#pragma unroll
  for (int kc = 0; kc < 2; ++kc)
    qf[kc] = *reinterpret_cast<const bf16x8*>(
        Q + base + (size_t)(qt * 128 + w * 16 + lq) * 64 + kc * 32 + quad * 8);

  // staging: slot = t (512 threads cover 512 16B slots); row = slot>>3;
  // source chunk = (slot&7) ^ s(row)
  const int row_s = t >> 3;
  const int sr_s = (row_s & 3) | (((row_s >> 3) & 1) << 2);
  const int cl_s = (t & 7) ^ sr_s;
  const int ko = row_s * 64 + cl_s * 8;     // K: [key][64]
  const int vo = row_s * 2048 + cl_s * 8;   // Vt: [d][2048]

  f32x4 O[4];
  f32x4 Lacc = f32x4{0.f, 0.f, 0.f, 0.f};
#pragma unroll
  for (int dg = 0; dg < 4; ++dg) O[dg] = f32x4{0.f, 0.f, 0.f, 0.f};

  const short oneb = (short)0x3F80;  // bf16 1.0
  const bf16x8 ones8 = {oneb, oneb, oneb, oneb, oneb, oneb, oneb, oneb};

  // prologue: stage tile 0 into buffer 0 (1 K + 1 V load per thread)
  {
    const u16* kgp = K + base;
    const u16* vgp = Vt + base;
    async16(kgp + ko, &Ks[0][(w * 64) * 8]);
    async16(vgp + vo, &Vs[0][(w * 64) * 8]);
  }

  for (int kt = 0; kt < 32; ++kt) {
    const int cur = kt & 1;
    __syncthreads();  // drains DMA into buf[cur]; prior reads of buf[cur^1] done
    if (kt < 31) {
      const u16* kgp = K + base + (size_t)(kt + 1) * 4096;
      const u16* vgp = Vt + base + (size_t)(kt + 1) * 64;
      const int nb = cur ^ 1;
      async16(kgp + ko, &Ks[nb][(w * 64) * 8]);
      async16(vgp + vo, &Vs[nb][(w * 64) * 8]);
    }

#pragma unroll
    for (int half = 0; half < 2; ++half) {
      // permuted K rows: key = half*32 + (lq>>2)*8 + kg2*4 + (lq&3)
      const int rb = half * 32 + ((lq >> 2) << 3) + (lq & 3);
      bf16x8 kf[2][2];
#pragma unroll
      for (int kg2 = 0; kg2 < 2; ++kg2) {
        const int krow = rb + kg2 * 4;
        kf[kg2][0] = *reinterpret_cast<const bf16x8*>(
            &Ks[cur][krow * 64 + (quad ^ swk) * 8]);          // d chunk = quad
        kf[kg2][1] = *reinterpret_cast<const bf16x8*>(
            &Ks[cur][krow * 64 + ((quad + 4) ^ swk) * 8]);    // d chunk = quad+4
      }

      // V B-frags (16x16x32): B[k=key][n=d], keys half*32+quad*8..+7 contiguous
      bf16x8 vbf[4];
#pragma unroll
      for (int dg = 0; dg < 4; ++dg)
        vbf[dg] = *reinterpret_cast<const bf16x8*>(
            &Vs[cur][(dg * 16 + lq) * 64 + ((half * 4 + quad) ^ swv) * 8]);

      // S^T[key][q] for the 32-key half: two sub-MFMAs x two d-chunks
      f32x4 z0 = {0.f, 0.f, 0.f, 0.f}, z1 = {0.f, 0.f, 0.f, 0.f};
      z0 = __builtin_amdgcn_mfma_f32_16x16x32_bf16(kf[0][0], qf[0], z0, 0, 0, 0);
      z0 = __builtin_amdgcn_mfma_f32_16x16x32_bf16(kf[0][1], qf[1], z0, 0, 0, 0);
      z1 = __builtin_amdgcn_mfma_f32_16x16x32_bf16(kf[1][0], qf[0], z1, 0, 0, 0);
      z1 = __builtin_amdgcn_mfma_f32_16x16x32_bf16(kf[1][1], qf[1], z1, 0, 0, 0);

      const float cf = cft[half];
      const float p0 = fexp2(__builtin_fmaf(z0[0], cf, -MC));
      const float p1 = fexp2(__builtin_fmaf(z0[1], cf, -MC));
      const float p2 = fexp2(__builtin_fmaf(z0[2], cf, -MC));
      const float p3 = fexp2(__builtin_fmaf(z0[3], cf, -MC));
      const float p4 = fexp2(__builtin_fmaf(z1[0], cf, -MC));
      const float p5 = fexp2(__builtin_fmaf(z1[1], cf, -MC));
      const float p6 = fexp2(__builtin_fmaf(z1[2], cf, -MC));
      const float p7 = fexp2(__builtin_fmaf(z1[3], cf, -MC));

      u32x4 pk;
      pk.x = pk2bf(p0, p1);
      pk.y = pk2bf(p2, p3);
      pk.z = pk2bf(p4, p5);
      pk.w = pk2bf(p6, p7);
      const bf16x8 pa = __builtin_bit_cast(bf16x8, pk);

      // softmax denominator: C reg r = sum_k P[q=quad*4+r][k]
      Lacc = __builtin_amdgcn_mfma_f32_16x16x32_bf16(pa, ones8, Lacc, 0, 0, 0);
#pragma unroll
      for (int dg = 0; dg < 4; ++dg)
        O[dg] = __builtin_amdgcn_mfma_f32_16x16x32_bf16(pa, vbf[dg], O[dg], 0, 0, 0);
    }
  }

  // epilogue: O C-layout: q = quad*4+r (row), d = dg*16+lq (col);
  // Lacc has the matching row layout -- no cross-lane reduce needed.
#pragma unroll
  for (int r = 0; r < 4; ++r) {
    const float iv = 1.f / Lacc[r];
    const size_t trow = (size_t)(qt * 128 + w * 16 + quad * 4 + r);
    float* op = out + ((size_t)b * 2048 + trow) * 1024 + h * 64 + lq;
#pragma unroll
    for (int dg = 0; dg < 4; ++dg) op[dg * 16] = O[dg][r] * iv;
  }
}

extern "C" void kernel_launch(void* const* d_in, const int* in_sizes, int n_in,
                              void* d_out, int out_size, void* d_ws, size_t ws_size,
                              hipStream_t stream) {
  (void)in_sizes; (void)n_in; (void)out_size; (void)ws_size;
  const float* x = (const float*)d_in[0];
  const float* Wq = (const float*)d_in[1];
  const float* Wk = (const float*)d_in[2];
  const float* Wv = (const float*)d_in[3];
  const float* wip = (const float*)d_in[4];
  float* out = (float*)d_out;

  u16* xb = (u16*)d_ws;
  u16* wb = xb + 8388608;
  u16* qb = wb + 3145728;
  u16* kb = qb + 8388608;
  u16* vb = kb + 8388608;   // holds V^T [B][H][64][2048]

  cvt_all<<<11264, 256, 0, stream>>>(x, Wq, Wk, Wv, xb, wb);
  qkv_gemm<<<dim3(64, 8, 3), 256, 0, stream>>>(xb, wb, qb);
  palace_attn<<<dim3(64, 16, 1), 512, 0, stream>>>(qb, kb, vb, out, wip);
}

// Round 10
// 212.366 us; speedup vs baseline: 1.0737x; 1.0737x over previous
//
#include <hip/hip_runtime.h>

typedef unsigned short u16;
typedef unsigned int u32;
typedef short bf16x8 __attribute__((ext_vector_type(8)));
typedef float f32x4 __attribute__((ext_vector_type(4)));
typedef u32 u32x4 __attribute__((ext_vector_type(4)));

#define AS_GLOBAL __attribute__((address_space(1)))
#define AS_LDS __attribute__((address_space(3)))

__device__ __forceinline__ void async16(const void* g, void* l) {
  __builtin_amdgcn_global_load_lds((const AS_GLOBAL u32*)g, (AS_LDS u32*)l, 16, 0, 0);
}

__device__ __forceinline__ u16 f2bf(float f) {
  u32 u = __builtin_bit_cast(u32, f);
  u += 0x7FFFu + ((u >> 16) & 1u);   // RNE
  return (u16)(u >> 16);
}

__device__ __forceinline__ u32 pk2bf(float lo, float hi) {
  return __builtin_amdgcn_perm(__builtin_bit_cast(u32, hi),
                               __builtin_bit_cast(u32, lo), 0x07060302u);
}

__device__ __forceinline__ float fexp2(float x) {
#if __has_builtin(__builtin_amdgcn_exp2f)
  return __builtin_amdgcn_exp2f(x);
#else
  return exp2f(x);
#endif
}

// ---------------- Pass A: all four f32 -> bf16 converts in one launch ----------------
__global__ __launch_bounds__(256) void cvt_all(const float* __restrict__ x,
                                               const float* __restrict__ wq,
                                               const float* __restrict__ wk,
                                               const float* __restrict__ wv,
                                               u16* __restrict__ xb,
                                               u16* __restrict__ wb) {
  const int blk = blockIdx.x;
  const float* src;
  u16* dst;
  int i;
  if (blk < 8192) {
    src = x; dst = xb; i = blk * 256 + threadIdx.x;
  } else if (blk < 9216) {
    src = wq; dst = wb; i = (blk - 8192) * 256 + threadIdx.x;
  } else if (blk < 10240) {
    src = wk; dst = wb + 1048576; i = (blk - 9216) * 256 + threadIdx.x;
  } else {
    src = wv; dst = wb + 2097152; i = (blk - 10240) * 256 + threadIdx.x;
  }
  float4 f = reinterpret_cast<const float4*>(src)[i];
  ushort4 o;
  o.x = f2bf(f.x); o.y = f2bf(f.y); o.z = f2bf(f.z); o.w = f2bf(f.w);
  reinterpret_cast<ushort4*>(dst)[i] = o;
}

// ---------------- Pass B: QKV projection GEMM (C = X * W^T) ----------------
// ROUND-7 PROVEN VERSION, UNCHANGED (wide-store epilogue win: 88 -> ~60 us).
// K-loop: 256 thr, 2x2 waves of 64x64, BK=64, double-buffered LDS, one
// __syncthreads per k-tile, conflict-free chunk-XOR swizzle. Epilogue stages
// C through LDS and emits 8 x global_store_dwordx4 per thread.
// grid: x = m-tile (64), y = n-tile (8), z = matrix (3)
// z=0 (Q), z=1 (K): out [B][H][T][64]; z=2 (V): out TRANSPOSED [B][H][64][T]
__global__ __launch_bounds__(256, 2) void qkv_gemm(const u16* __restrict__ X,
                                                   const u16* __restrict__ W,
                                                   u16* __restrict__ O) {
  const int z = blockIdx.z;
  const u16* Wz = W + (size_t)z * (1024 * 1024);
  u16* Oz = O + (size_t)z * (8192 * 1024);

  // unified 64KB: SMEM[0..1] = A dbuf, SMEM[2..3] = B dbuf; epilogue reuses
  // SMEM[w] as wave-private staging (8192 u16 each >= 64*80).
  __shared__ __align__(16) u16 SMEM[4][8192];

  const int t = threadIdx.x;
  const int lane = t & 63, w = t >> 6, quad = lane >> 4, lq = lane & 15;
  const int wm = (w >> 1) * 64, wn = (w & 1) * 64;
  const int sw = lq & 7;
  const size_t m0 = (size_t)blockIdx.x * 128;
  const int n0 = blockIdx.y * 128;

  // staging source offsets (u16 units): slot -> (row, pre-swizzled chunk)
  int off[4];
#pragma unroll
  for (int j = 0; j < 4; ++j) {
    const int s = j * 256 + t, row = s >> 3, c = (s & 7) ^ (row & 7);
    off[j] = row * 1024 + c * 8;
  }
  const u16* gA = X + m0 * 1024;
  const u16* gB = Wz + (size_t)n0 * 1024;

  f32x4 acc[4][4];
#pragma unroll
  for (int i = 0; i < 4; ++i)
#pragma unroll
    for (int j = 0; j < 4; ++j) acc[i][j] = f32x4{0.f, 0.f, 0.f, 0.f};

  // 8 gload_lds(16B)/thread stages one 128x64 A panel + 128x64 B panel
  auto stage = [&](int kt, int nb) {
    const u16* ga = gA + kt * 64;
    const u16* gb = gB + kt * 64;
#pragma unroll
    for (int j = 0; j < 4; ++j)
      async16(ga + off[j], &SMEM[nb][(j * 256 + t) * 8]);
#pragma unroll
    for (int j = 0; j < 4; ++j)
      async16(gb + off[j], &SMEM[2 + nb][(j * 256 + t) * 8]);
  };

  // prologue: stage tile 0 into buffer 0
  stage(0, 0);

  for (int kt = 0; kt < 16; ++kt) {
    const int cur = kt & 1;
    __syncthreads();                    // tile kt resident; buf[cur^1] free
    if (kt < 15) stage(kt + 1, cur ^ 1);

    bf16x8 Af[4][2], Bf[4][2];
#pragma unroll
    for (int i = 0; i < 4; ++i)
#pragma unroll
      for (int ks = 0; ks < 2; ++ks) {
        Af[i][ks] = *reinterpret_cast<const bf16x8*>(
            &SMEM[cur][(wm + i * 16 + lq) * 64 + ((ks * 4 + quad) ^ sw) * 8]);
        Bf[i][ks] = *reinterpret_cast<const bf16x8*>(
            &SMEM[2 + cur][(wn + i * 16 + lq) * 64 + ((ks * 4 + quad) ^ sw) * 8]);
      }
#pragma unroll
    for (int i = 0; i < 4; ++i)
#pragma unroll
      for (int j = 0; j < 4; ++j) {
        acc[i][j] = __builtin_amdgcn_mfma_f32_16x16x32_bf16(Af[i][0], Bf[j][0], acc[i][j], 0, 0, 0);
        acc[i][j] = __builtin_amdgcn_mfma_f32_16x16x32_bf16(Af[i][1], Bf[j][1], acc[i][j], 0, 0, 0);
      }
  }

  // ---- wide-store epilogue ----
  __syncthreads();                      // all LDS reads of the main loop done
  u16* ep = &SMEM[w][0];                // wave-private region, layout [64][80]
  if (z != 2) {
    // LDS row = local m (0..63), col = local n (0..63)
#pragma unroll
    for (int i = 0; i < 4; ++i)
#pragma unroll
      for (int j = 0; j < 4; ++j)
#pragma unroll
        for (int r = 0; r < 4; ++r)
          ep[(i * 16 + quad * 4 + r) * 80 + j * 16 + lq] = f2bf(acc[i][j][r]);
  } else {
    // transposed: LDS row = local n (=d), col = local m (=t)
#pragma unroll
    for (int i = 0; i < 4; ++i)
#pragma unroll
      for (int j = 0; j < 4; ++j)
#pragma unroll
        for (int r = 0; r < 4; ++r)
          ep[(j * 16 + lq) * 80 + i * 16 + quad * 4 + r] = f2bf(acc[i][j][r]);
  }
  asm volatile("s_waitcnt lgkmcnt(0)" ::: "memory");  // own-wave writes visible

  const int r8 = lane >> 3, c8 = lane & 7;            // 8 rows x 8 chunks
  const size_t ms = m0 + wm;
  const size_t bb = ms >> 11, tt0 = ms & 2047;
  const int hh = (n0 + wn) >> 6;
  if (z != 2) {
    // wave tile = contiguous 8KB at ((bb*16+hh)*2048 + tt0)*64
    u16* gbase = Oz + ((bb * 16 + hh) * 2048 + tt0) * 64;
#pragma unroll
    for (int kq = 0; kq < 8; ++kq) {
      const int row = kq * 8 + r8;
      bf16x8 v = *reinterpret_cast<const bf16x8*>(&ep[row * 80 + c8 * 8]);
      *reinterpret_cast<bf16x8*>(&gbase[(size_t)row * 64 + c8 * 8]) = v;
    }
  } else {
    // wave tile = 64 rows (d) of 128B at stride 4KB
    u16* gbase = Oz + ((size_t)(bb * 16 + hh) * 64) * 2048 + tt0;
#pragma unroll
    for (int kq = 0; kq < 8; ++kq) {
      const int row = kq * 8 + r8;
      bf16x8 v = *reinterpret_cast<const bf16x8*>(&ep[row * 80 + c8 * 8]);
      *reinterpret_cast<bf16x8*>(&gbase[(size_t)row * 2048 + c8 * 8]) = v;
    }
  }
}

// ---------------- Pass C: flash attention, S^T-form, full-rate 16x16x32 PV ----------------
// Round-10: REVERT to round-8 shape (8 waves x 32 q/wave, 256-q tile, grid
// 64x8 -- best measured 79.1 us; round-9's 16-q split doubled per-CU LDS-read
// traffic and regressed). NEW single lever: 4-buffer / prefetch-3 /
// counted-vmcnt DMA pipeline (the structure that ran correct on qkv r5/r6;
// its null there is uninformative -- qkv was store-bound at the time).
// Replaces __syncthreads' vmcnt(0) drain: per kt, vmcnt(4) retires ONLY tile
// kt's 2 loads (kt+1,kt+2's 4 stay in flight across the raw s_barrier).
// Race-free: stage(kt+3) overwrites buf[(kt-1)&3] only AFTER the barrier
// proving all waves completed iter kt-1's compute (all ds_reads consumed).
// LDS 4 x (8+8) KB = 64 KB -> still 2 blocks/CU.
//
// Key-permuted S^T (unchanged): for 32-key half `half`, sub-MFMA kg2 reads
// K row key(m) = half*32 + (m>>2)*8 + kg2*4 + (m&3), so each lane's 8 P
// values sit at keys quad*8+{0..7} == the 16x16x32 A-frag layout. PV at full
// 2xK rate; V B-frag one contiguous bf16x8 per dg. Row-sum via
// mfma(pa, ones, Lacc). Palace mask: q-slot = (w&1)*4 + qg*2 + (lq>>3);
// key-slot = half*4 + quad, uniform over the lane's 8 keys.
// LDS swizzle: position = chunk ^ s(row), s(row) = (row&3) | (((row>>3)&1)<<2).
__global__ __launch_bounds__(512, 4) void palace_attn(const u16* __restrict__ Q,
                                                      const u16* __restrict__ K,
                                                      const u16* __restrict__ Vt,
                                                      float* __restrict__ out,
                                                      const float* __restrict__ wptr) {
  const int bh = blockIdx.x, qt = blockIdx.y;
  const int h = bh & 15, b = bh >> 4;
  const size_t base = (size_t)bh * (2048 * 64);

  __shared__ __align__(16) u16 Ks[4][64 * 64];   // [key][d], swizzled 16B chunks
  __shared__ __align__(16) u16 Vs[4][64 * 64];   // [d][key], swizzled 16B chunks

  const int t = threadIdx.x;
  const int w = t >> 6, lane = t & 63, quad = lane >> 4, lq = lane & 15;
  const int lq3 = lq >> 3;
  const int swk = (lq & 3) | (((lq >> 2) & 1) << 2);  // s(row) for permuted K rows
  const int swv = (lq & 3) | (lq3 << 2);              // s(d) for V rows d=dg*16+lq
  const float sig = 1.f / (1.f + __expf(-wptr[0]));
  const float Ci = 0.125f * 1.44269504f;   // intra coeff (scale * log2 e)
  const float Co = Ci * sig;               // inter coeff
  const float MC = 14.4269504f;            // fixed softmax offset: 10 * log2 e

  // palace mask: q-slot = (w&1)*4 + qg*2 + lq3; key-slot = half*4 + quad
  const int qs0 = (w & 1) * 4;
  float cft[2][2];
#pragma unroll
  for (int half = 0; half < 2; ++half)
#pragma unroll
    for (int qg = 0; qg < 2; ++qg)
      cft[half][qg] = (half * 4 + quad == qs0 + qg * 2 + lq3) ? Ci : Co;

  // Q B-frags (16x16x32): B[k=d][n=q], q = qt*256 + w*32 + qg*16 + lq
  bf16x8 qf[2][2];
#pragma unroll
  for (int qg = 0; qg < 2; ++qg)
#pragma unroll
    for (int kc = 0; kc < 2; ++kc)
      qf[qg][kc] = *reinterpret_cast<const bf16x8*>(
          Q + base + (size_t)(qt * 256 + w * 32 + qg * 16 + lq) * 64 + kc * 32 + quad * 8);

  // staging: slot = t (512 threads cover 512 16B slots); row = slot>>3;
  // source chunk = (slot&7) ^ s(row)
  const int row_s = t >> 3;
  const int sr_s = (row_s & 3) | (((row_s >> 3) & 1) << 2);
  const int cl_s = (t & 7) ^ sr_s;
  const int ko = row_s * 64 + cl_s * 8;     // K: [key][64]
  const int vo = row_s * 2048 + cl_s * 8;   // Vt: [d][2048]

  f32x4 O[2][4];
  f32x4 Lacc[2];
#pragma unroll
  for (int qg = 0; qg < 2; ++qg) {
    Lacc[qg] = f32x4{0.f, 0.f, 0.f, 0.f};
#pragma unroll
    for (int dg = 0; dg < 4; ++dg) O[qg][dg] = f32x4{0.f, 0.f, 0.f, 0.f};
  }

  const short oneb = (short)0x3F80;  // bf16 1.0
  const bf16x8 ones8 = {oneb, oneb, oneb, oneb, oneb, oneb, oneb, oneb};

  // stage tile kt into buffer nb (1 K + 1 V load per thread)
  auto stage = [&](int kt, int nb) {
    const u16* kgp = K + base + (size_t)kt * 4096;
    const u16* vgp = Vt + base + (size_t)kt * 64;
    async16(kgp + ko, &Ks[nb][(w * 64) * 8]);
    async16(vgp + vo, &Vs[nb][(w * 64) * 8]);
  };

  auto compute_tile = [&](int cur) {
#pragma unroll
    for (int half = 0; half < 2; ++half) {
      // permuted K rows: key = half*32 + (lq>>2)*8 + kg2*4 + (lq&3)
      const int rb = half * 32 + ((lq >> 2) << 3) + (lq & 3);
      bf16x8 kf[2][2];
#pragma unroll
      for (int kg2 = 0; kg2 < 2; ++kg2) {
        const int krow = rb + kg2 * 4;
        kf[kg2][0] = *reinterpret_cast<const bf16x8*>(
            &Ks[cur][krow * 64 + (quad ^ swk) * 8]);          // d chunk = quad
        kf[kg2][1] = *reinterpret_cast<const bf16x8*>(
            &Ks[cur][krow * 64 + ((quad + 4) ^ swk) * 8]);    // d chunk = quad+4
      }

      // V B-frags (16x16x32): B[k=key][n=d], keys half*32+quad*8..+7 contiguous
      bf16x8 vbf[4];
#pragma unroll
      for (int dg = 0; dg < 4; ++dg)
        vbf[dg] = *reinterpret_cast<const bf16x8*>(
            &Vs[cur][(dg * 16 + lq) * 64 + ((half * 4 + quad) ^ swv) * 8]);

#pragma unroll
      for (int qg = 0; qg < 2; ++qg) {
        // S^T[key][q] for the 32-key half: two sub-MFMAs x two d-chunks
        f32x4 z0 = {0.f, 0.f, 0.f, 0.f}, z1 = {0.f, 0.f, 0.f, 0.f};
        z0 = __builtin_amdgcn_mfma_f32_16x16x32_bf16(kf[0][0], qf[qg][0], z0, 0, 0, 0);
        z0 = __builtin_amdgcn_mfma_f32_16x16x32_bf16(kf[0][1], qf[qg][1], z0, 0, 0, 0);
        z1 = __builtin_amdgcn_mfma_f32_16x16x32_bf16(kf[1][0], qf[qg][0], z1, 0, 0, 0);
        z1 = __builtin_amdgcn_mfma_f32_16x16x32_bf16(kf[1][1], qf[qg][1], z1, 0, 0, 0);

        const float cf = cft[half][qg];
        const float p0 = fexp2(__builtin_fmaf(z0[0], cf, -MC));
        const float p1 = fexp2(__builtin_fmaf(z0[1], cf, -MC));
        const float p2 = fexp2(__builtin_fmaf(z0[2], cf, -MC));
        const float p3 = fexp2(__builtin_fmaf(z0[3], cf, -MC));
        const float p4 = fexp2(__builtin_fmaf(z1[0], cf, -MC));
        const float p5 = fexp2(__builtin_fmaf(z1[1], cf, -MC));
        const float p6 = fexp2(__builtin_fmaf(z1[2], cf, -MC));
        const float p7 = fexp2(__builtin_fmaf(z1[3], cf, -MC));

        u32x4 pk;
        pk.x = pk2bf(p0, p1);
        pk.y = pk2bf(p2, p3);
        pk.z = pk2bf(p4, p5);
        pk.w = pk2bf(p6, p7);
        const bf16x8 pa = __builtin_bit_cast(bf16x8, pk);

        // softmax denominator: C reg r = sum_k P[q=qg*16+quad*4+r][k]
        Lacc[qg] = __builtin_amdgcn_mfma_f32_16x16x32_bf16(pa, ones8, Lacc[qg], 0, 0, 0);
#pragma unroll
        for (int dg = 0; dg < 4; ++dg)
          O[qg][dg] = __builtin_amdgcn_mfma_f32_16x16x32_bf16(pa, vbf[dg], O[qg][dg], 0, 0, 0);
      }
    }
  };

  // prologue: 3 tiles in flight
  stage(0, 0);
  stage(1, 1);
  stage(2, 2);

  for (int kt = 0; kt < 29; ++kt) {
    // retire tile kt's 2 loads (4 newest = tiles kt+1, kt+2 stay in flight)
    asm volatile("s_waitcnt vmcnt(4)" ::: "memory");
    __builtin_amdgcn_s_barrier();
    __builtin_amdgcn_sched_barrier(0);
    stage(kt + 3, (kt + 3) & 3);
    compute_tile(kt & 3);
  }
  // kt = 29: tiles 29,30,31 outstanding (6) -> retire 29
  asm volatile("s_waitcnt vmcnt(4)" ::: "memory");
  __builtin_amdgcn_s_barrier();
  __builtin_amdgcn_sched_barrier(0);
  compute_tile(1);
  // kt = 30
  asm volatile("s_waitcnt vmcnt(2)" ::: "memory");
  __builtin_amdgcn_s_barrier();
  __builtin_amdgcn_sched_barrier(0);
  compute_tile(2);
  // kt = 31
  asm volatile("s_waitcnt vmcnt(0)" ::: "memory");
  __builtin_amdgcn_s_barrier();
  __builtin_amdgcn_sched_barrier(0);
  compute_tile(3);

  // epilogue: O C-layout: q = qg*16+quad*4+r (row), d = dg*16+lq (col);
  // Lacc has the matching row layout -- no cross-lane reduce needed.
#pragma unroll
  for (int qg = 0; qg < 2; ++qg) {
#pragma unroll
    for (int r = 0; r < 4; ++r) {
      const float iv = 1.f / Lacc[qg][r];
      const size_t trow = (size_t)(qt * 256 + w * 32 + qg * 16 + quad * 4 + r);
      float* op = out + ((size_t)b * 2048 + trow) * 1024 + h * 64 + lq;
#pragma unroll
      for (int dg = 0; dg < 4; ++dg) op[dg * 16] = O[qg][dg][r] * iv;
    }
  }
}

extern "C" void kernel_launch(void* const* d_in, const int* in_sizes, int n_in,
                              void* d_out, int out_size, void* d_ws, size_t ws_size,
                              hipStream_t stream) {
  (void)in_sizes; (void)n_in; (void)out_size; (void)ws_size;
  const float* x = (const float*)d_in[0];
  const float* Wq = (const float*)d_in[1];
  const float* Wk = (const float*)d_in[2];
  const float* Wv = (const float*)d_in[3];
  const float* wip = (const float*)d_in[4];
  float* out = (float*)d_out;

  u16* xb = (u16*)d_ws;
  u16* wb = xb + 8388608;
  u16* qb = wb + 3145728;
  u16* kb = qb + 8388608;
  u16* vb = kb + 8388608;   // holds V^T [B][H][64][2048]

  cvt_all<<<11264, 256, 0, stream>>>(x, Wq, Wk, Wv, xb, wb);
  qkv_gemm<<<dim3(64, 8, 3), 256, 0, stream>>>(xb, wb, qb);
  palace_attn<<<dim3(64, 8, 1), 512, 0, stream>>>(qb, kb, vb, out, wip);
}

// Round 11
// 212.326 us; speedup vs baseline: 1.0740x; 1.0002x over previous
//
#include <hip/hip_runtime.h>

typedef unsigned short u16;
typedef unsigned int u32;
typedef short bf16x8 __attribute__((ext_vector_type(8)));
typedef float f32x4 __attribute__((ext_vector_type(4)));
typedef u32 u32x4 __attribute__((ext_vector_type(4)));

#define AS_GLOBAL __attribute__((address_space(1)))
#define AS_LDS __attribute__((address_space(3)))

__device__ __forceinline__ void async16(const void* g, void* l) {
  __builtin_amdgcn_global_load_lds((const AS_GLOBAL u32*)g, (AS_LDS u32*)l, 16, 0, 0);
}

__device__ __forceinline__ u16 f2bf(float f) {
  u32 u = __builtin_bit_cast(u32, f);
  u += 0x7FFFu + ((u >> 16) & 1u);   // RNE
  return (u16)(u >> 16);
}

__device__ __forceinline__ u32 pk2bf(float lo, float hi) {
  return __builtin_amdgcn_perm(__builtin_bit_cast(u32, hi),
                               __builtin_bit_cast(u32, lo), 0x07060302u);
}

__device__ __forceinline__ float fexp2(float x) {
#if __has_builtin(__builtin_amdgcn_exp2f)
  return __builtin_amdgcn_exp2f(x);
#else
  return exp2f(x);
#endif
}

// ---------------- Pass A: all four f32 -> bf16 converts in one launch ----------------
__global__ __launch_bounds__(256) void cvt_all(const float* __restrict__ x,
                                               const float* __restrict__ wq,
                                               const float* __restrict__ wk,
                                               const float* __restrict__ wv,
                                               u16* __restrict__ xb,
                                               u16* __restrict__ wb) {
  const int blk = blockIdx.x;
  const float* src;
  u16* dst;
  int i;
  if (blk < 8192) {
    src = x; dst = xb; i = blk * 256 + threadIdx.x;
  } else if (blk < 9216) {
    src = wq; dst = wb; i = (blk - 8192) * 256 + threadIdx.x;
  } else if (blk < 10240) {
    src = wk; dst = wb + 1048576; i = (blk - 9216) * 256 + threadIdx.x;
  } else {
    src = wv; dst = wb + 2097152; i = (blk - 10240) * 256 + threadIdx.x;
  }
  float4 f = reinterpret_cast<const float4*>(src)[i];
  ushort4 o;
  o.x = f2bf(f.x); o.y = f2bf(f.y); o.z = f2bf(f.z); o.w = f2bf(f.w);
  reinterpret_cast<ushort4*>(dst)[i] = o;
}

// ---------------- Pass B: QKV projection GEMM (C = X * W^T) ----------------
// ROUND-7 PROVEN VERSION, UNCHANGED (wide-store epilogue win: 88 -> ~60 us).
// K-loop: 256 thr, 2x2 waves of 64x64, BK=64, double-buffered LDS, one
// __syncthreads per k-tile, conflict-free chunk-XOR swizzle. Epilogue stages
// C through LDS and emits 8 x global_store_dwordx4 per thread.
// grid: x = m-tile (64), y = n-tile (8), z = matrix (3)
// z=0 (Q), z=1 (K): out [B][H][T][64]; z=2 (V): out TRANSPOSED [B][H][64][T]
__global__ __launch_bounds__(256, 2) void qkv_gemm(const u16* __restrict__ X,
                                                   const u16* __restrict__ W,
                                                   u16* __restrict__ O) {
  const int z = blockIdx.z;
  const u16* Wz = W + (size_t)z * (1024 * 1024);
  u16* Oz = O + (size_t)z * (8192 * 1024);

  // unified 64KB: SMEM[0..1] = A dbuf, SMEM[2..3] = B dbuf; epilogue reuses
  // SMEM[w] as wave-private staging (8192 u16 each >= 64*80).
  __shared__ __align__(16) u16 SMEM[4][8192];

  const int t = threadIdx.x;
  const int lane = t & 63, w = t >> 6, quad = lane >> 4, lq = lane & 15;
  const int wm = (w >> 1) * 64, wn = (w & 1) * 64;
  const int sw = lq & 7;
  const size_t m0 = (size_t)blockIdx.x * 128;
  const int n0 = blockIdx.y * 128;

  // staging source offsets (u16 units): slot -> (row, pre-swizzled chunk)
  int off[4];
#pragma unroll
  for (int j = 0; j < 4; ++j) {
    const int s = j * 256 + t, row = s >> 3, c = (s & 7) ^ (row & 7);
    off[j] = row * 1024 + c * 8;
  }
  const u16* gA = X + m0 * 1024;
  const u16* gB = Wz + (size_t)n0 * 1024;

  f32x4 acc[4][4];
#pragma unroll
  for (int i = 0; i < 4; ++i)
#pragma unroll
    for (int j = 0; j < 4; ++j) acc[i][j] = f32x4{0.f, 0.f, 0.f, 0.f};

  // 8 gload_lds(16B)/thread stages one 128x64 A panel + 128x64 B panel
  auto stage = [&](int kt, int nb) {
    const u16* ga = gA + kt * 64;
    const u16* gb = gB + kt * 64;
#pragma unroll
    for (int j = 0; j < 4; ++j)
      async16(ga + off[j], &SMEM[nb][(j * 256 + t) * 8]);
#pragma unroll
    for (int j = 0; j < 4; ++j)
      async16(gb + off[j], &SMEM[2 + nb][(j * 256 + t) * 8]);
  };

  // prologue: stage tile 0 into buffer 0
  stage(0, 0);

  for (int kt = 0; kt < 16; ++kt) {
    const int cur = kt & 1;
    __syncthreads();                    // tile kt resident; buf[cur^1] free
    if (kt < 15) stage(kt + 1, cur ^ 1);

    bf16x8 Af[4][2], Bf[4][2];
#pragma unroll
    for (int i = 0; i < 4; ++i)
#pragma unroll
      for (int ks = 0; ks < 2; ++ks) {
        Af[i][ks] = *reinterpret_cast<const bf16x8*>(
            &SMEM[cur][(wm + i * 16 + lq) * 64 + ((ks * 4 + quad) ^ sw) * 8]);
        Bf[i][ks] = *reinterpret_cast<const bf16x8*>(
            &SMEM[2 + cur][(wn + i * 16 + lq) * 64 + ((ks * 4 + quad) ^ sw) * 8]);
      }
#pragma unroll
    for (int i = 0; i < 4; ++i)
#pragma unroll
      for (int j = 0; j < 4; ++j) {
        acc[i][j] = __builtin_amdgcn_mfma_f32_16x16x32_bf16(Af[i][0], Bf[j][0], acc[i][j], 0, 0, 0);
        acc[i][j] = __builtin_amdgcn_mfma_f32_16x16x32_bf16(Af[i][1], Bf[j][1], acc[i][j], 0, 0, 0);
      }
  }

  // ---- wide-store epilogue ----
  __syncthreads();                      // all LDS reads of the main loop done
  u16* ep = &SMEM[w][0];                // wave-private region, layout [64][80]
  if (z != 2) {
    // LDS row = local m (0..63), col = local n (0..63)
#pragma unroll
    for (int i = 0; i < 4; ++i)
#pragma unroll
      for (int j = 0; j < 4; ++j)
#pragma unroll
        for (int r = 0; r < 4; ++r)
          ep[(i * 16 + quad * 4 + r) * 80 + j * 16 + lq] = f2bf(acc[i][j][r]);
  } else {
    // transposed: LDS row = local n (=d), col = local m (=t)
#pragma unroll
    for (int i = 0; i < 4; ++i)
#pragma unroll
      for (int j = 0; j < 4; ++j)
#pragma unroll
        for (int r = 0; r < 4; ++r)
          ep[(j * 16 + lq) * 80 + i * 16 + quad * 4 + r] = f2bf(acc[i][j][r]);
  }
  asm volatile("s_waitcnt lgkmcnt(0)" ::: "memory");  // own-wave writes visible

  const int r8 = lane >> 3, c8 = lane & 7;            // 8 rows x 8 chunks
  const size_t ms = m0 + wm;
  const size_t bb = ms >> 11, tt0 = ms & 2047;
  const int hh = (n0 + wn) >> 6;
  if (z != 2) {
    // wave tile = contiguous 8KB at ((bb*16+hh)*2048 + tt0)*64
    u16* gbase = Oz + ((bb * 16 + hh) * 2048 + tt0) * 64;
#pragma unroll
    for (int kq = 0; kq < 8; ++kq) {
      const int row = kq * 8 + r8;
      bf16x8 v = *reinterpret_cast<const bf16x8*>(&ep[row * 80 + c8 * 8]);
      *reinterpret_cast<bf16x8*>(&gbase[(size_t)row * 64 + c8 * 8]) = v;
    }
  } else {
    // wave tile = 64 rows (d) of 128B at stride 4KB
    u16* gbase = Oz + ((size_t)(bb * 16 + hh) * 64) * 2048 + tt0;
#pragma unroll
    for (int kq = 0; kq < 8; ++kq) {
      const int row = kq * 8 + r8;
      bf16x8 v = *reinterpret_cast<const bf16x8*>(&ep[row * 80 + c8 * 8]);
      *reinterpret_cast<bf16x8*>(&gbase[(size_t)row * 2048 + c8 * 8]) = v;
    }
  }
}

// ---------------- Pass C: flash attention, S^T-form, full-rate 16x16x32 PV ----------------
// Round-11: r8 skeleton (8 waves x 32 q/wave, 256-q tile, 2-buffer
// __syncthreads pipeline -- best measured 79.1 us) + two DE-PHASING levers
// against the measured pattern "MFMA 42% / VALU 50% / LDS-read ~52%, wall =
// 2x max pipe" (barrier phase-locks all waves into read-phase then
// compute-phase):
//   1. Wave-staggered half order: wave w processes key-half (w&1) first, so
//      at any instant ~half the waves are in ds_read while the others MFMA.
//      (FP sum reorder only -- accumulators are per-wave.)
//   2. s_setprio(1) around the MFMA clusters (QK quad; Lacc+PV quint),
//      prio 0 during the exp/pack VALU stretch (T5: proven +4-7% on attn).
//
// Key-permuted S^T (unchanged): for 32-key half `half`, sub-MFMA kg2 reads
// K row key(m) = half*32 + (m>>2)*8 + kg2*4 + (m&3), so each lane's 8 P
// values sit at keys quad*8+{0..7} == the 16x16x32 A-frag layout. PV at full
// 2xK rate; V B-frag one contiguous bf16x8 per dg. Row-sum via
// mfma(pa, ones, Lacc). Palace mask: q-slot = (w&1)*4 + qg*2 + (lq>>3);
// key-slot = half*4 + quad, uniform over the lane's 8 keys.
// LDS swizzle: position = chunk ^ s(row), s(row) = (row&3) | (((row>>3)&1)<<2).
__global__ __launch_bounds__(512, 4) void palace_attn(const u16* __restrict__ Q,
                                                      const u16* __restrict__ K,
                                                      const u16* __restrict__ Vt,
                                                      float* __restrict__ out,
                                                      const float* __restrict__ wptr) {
  const int bh = blockIdx.x, qt = blockIdx.y;
  const int h = bh & 15, b = bh >> 4;
  const size_t base = (size_t)bh * (2048 * 64);

  __shared__ __align__(16) u16 Ks[2][64 * 64];   // [key][d], swizzled 16B chunks
  __shared__ __align__(16) u16 Vs[2][64 * 64];   // [d][key], swizzled 16B chunks

  const int t = threadIdx.x;
  const int w = t >> 6, lane = t & 63, quad = lane >> 4, lq = lane & 15;
  const int lq3 = lq >> 3;
  const int swk = (lq & 3) | (((lq >> 2) & 1) << 2);  // s(row) for permuted K rows
  const int swv = (lq & 3) | (lq3 << 2);              // s(d) for V rows d=dg*16+lq
  const float sig = 1.f / (1.f + __expf(-wptr[0]));
  const float Ci = 0.125f * 1.44269504f;   // intra coeff (scale * log2 e)
  const float Co = Ci * sig;               // inter coeff
  const float MC = 14.4269504f;            // fixed softmax offset: 10 * log2 e

  // palace mask: q-slot = (w&1)*4 + qg*2 + lq3; key-slot = half*4 + quad
  const int qs0 = (w & 1) * 4;
  float cft[2][2];
#pragma unroll
  for (int half = 0; half < 2; ++half)
#pragma unroll
    for (int qg = 0; qg < 2; ++qg)
      cft[half][qg] = (half * 4 + quad == qs0 + qg * 2 + lq3) ? Ci : Co;

  // Q B-frags (16x16x32): B[k=d][n=q], q = qt*256 + w*32 + qg*16 + lq
  bf16x8 qf[2][2];
#pragma unroll
  for (int qg = 0; qg < 2; ++qg)
#pragma unroll
    for (int kc = 0; kc < 2; ++kc)
      qf[qg][kc] = *reinterpret_cast<const bf16x8*>(
          Q + base + (size_t)(qt * 256 + w * 32 + qg * 16 + lq) * 64 + kc * 32 + quad * 8);

  // staging: slot = t (512 threads cover 512 16B slots); row = slot>>3;
  // source chunk = (slot&7) ^ s(row)
  const int row_s = t >> 3;
  const int sr_s = (row_s & 3) | (((row_s >> 3) & 1) << 2);
  const int cl_s = (t & 7) ^ sr_s;
  const int ko = row_s * 64 + cl_s * 8;     // K: [key][64]
  const int vo = row_s * 2048 + cl_s * 8;   // Vt: [d][2048]

  f32x4 O[2][4];
  f32x4 Lacc[2];
#pragma unroll
  for (int qg = 0; qg < 2; ++qg) {
    Lacc[qg] = f32x4{0.f, 0.f, 0.f, 0.f};
#pragma unroll
    for (int dg = 0; dg < 4; ++dg) O[qg][dg] = f32x4{0.f, 0.f, 0.f, 0.f};
  }

  const short oneb = (short)0x3F80;  // bf16 1.0
  const bf16x8 ones8 = {oneb, oneb, oneb, oneb, oneb, oneb, oneb, oneb};

  const int h0 = w & 1;  // wave-staggered half order

  // prologue: stage tile 0 into buffer 0 (1 K + 1 V load per thread)
  {
    const u16* kgp = K + base;
    const u16* vgp = Vt + base;
    async16(kgp + ko, &Ks[0][(w * 64) * 8]);
    async16(vgp + vo, &Vs[0][(w * 64) * 8]);
  }

  for (int kt = 0; kt < 32; ++kt) {
    const int cur = kt & 1;
    __syncthreads();  // drains DMA into buf[cur]; prior reads of buf[cur^1] done
    if (kt < 31) {
      const u16* kgp = K + base + (size_t)(kt + 1) * 4096;
      const u16* vgp = Vt + base + (size_t)(kt + 1) * 64;
      const int nb = cur ^ 1;
      async16(kgp + ko, &Ks[nb][(w * 64) * 8]);
      async16(vgp + vo, &Vs[nb][(w * 64) * 8]);
    }

#pragma unroll
    for (int hx = 0; hx < 2; ++hx) {
      const int half = hx ^ h0;  // waves process halves in opposite order
      // permuted K rows: key = half*32 + (lq>>2)*8 + kg2*4 + (lq&3)
      const int rb = half * 32 + ((lq >> 2) << 3) + (lq & 3);
      bf16x8 kf[2][2];
#pragma unroll
      for (int kg2 = 0; kg2 < 2; ++kg2) {
        const int krow = rb + kg2 * 4;
        kf[kg2][0] = *reinterpret_cast<const bf16x8*>(
            &Ks[cur][krow * 64 + (quad ^ swk) * 8]);          // d chunk = quad
        kf[kg2][1] = *reinterpret_cast<const bf16x8*>(
            &Ks[cur][krow * 64 + ((quad + 4) ^ swk) * 8]);    // d chunk = quad+4
      }

      // V B-frags (16x16x32): B[k=key][n=d], keys half*32+quad*8..+7 contiguous
      bf16x8 vbf[4];
#pragma unroll
      for (int dg = 0; dg < 4; ++dg)
        vbf[dg] = *reinterpret_cast<const bf16x8*>(
            &Vs[cur][(dg * 16 + lq) * 64 + ((half * 4 + quad) ^ swv) * 8]);

#pragma unroll
      for (int qg = 0; qg < 2; ++qg) {
        // S^T[key][q] for the 32-key half: two sub-MFMAs x two d-chunks
        f32x4 z0 = {0.f, 0.f, 0.f, 0.f}, z1 = {0.f, 0.f, 0.f, 0.f};
        __builtin_amdgcn_s_setprio(1);
        z0 = __builtin_amdgcn_mfma_f32_16x16x32_bf16(kf[0][0], qf[qg][0], z0, 0, 0, 0);
        z0 = __builtin_amdgcn_mfma_f32_16x16x32_bf16(kf[0][1], qf[qg][1], z0, 0, 0, 0);
        z1 = __builtin_amdgcn_mfma_f32_16x16x32_bf16(kf[1][0], qf[qg][0], z1, 0, 0, 0);
        z1 = __builtin_amdgcn_mfma_f32_16x16x32_bf16(kf[1][1], qf[qg][1], z1, 0, 0, 0);
        __builtin_amdgcn_s_setprio(0);

        const float cf = cft[half][qg];
        const float p0 = fexp2(__builtin_fmaf(z0[0], cf, -MC));
        const float p1 = fexp2(__builtin_fmaf(z0[1], cf, -MC));
        const float p2 = fexp2(__builtin_fmaf(z0[2], cf, -MC));
        const float p3 = fexp2(__builtin_fmaf(z0[3], cf, -MC));
        const float p4 = fexp2(__builtin_fmaf(z1[0], cf, -MC));
        const float p5 = fexp2(__builtin_fmaf(z1[1], cf, -MC));
        const float p6 = fexp2(__builtin_fmaf(z1[2], cf, -MC));
        const float p7 = fexp2(__builtin_fmaf(z1[3], cf, -MC));

        u32x4 pk;
        pk.x = pk2bf(p0, p1);
        pk.y = pk2bf(p2, p3);
        pk.z = pk2bf(p4, p5);
        pk.w = pk2bf(p6, p7);
        const bf16x8 pa = __builtin_bit_cast(bf16x8, pk);

        // softmax denominator: C reg r = sum_k P[q=qg*16+quad*4+r][k]
        __builtin_amdgcn_s_setprio(1);
        Lacc[qg] = __builtin_amdgcn_mfma_f32_16x16x32_bf16(pa, ones8, Lacc[qg], 0, 0, 0);
#pragma unroll
        for (int dg = 0; dg < 4; ++dg)
          O[qg][dg] = __builtin_amdgcn_mfma_f32_16x16x32_bf16(pa, vbf[dg], O[qg][dg], 0, 0, 0);
        __builtin_amdgcn_s_setprio(0);
      }
    }
  }

  // epilogue: O C-layout: q = qg*16+quad*4+r (row), d = dg*16+lq (col);
  // Lacc has the matching row layout -- no cross-lane reduce needed.
#pragma unroll
  for (int qg = 0; qg < 2; ++qg) {
#pragma unroll
    for (int r = 0; r < 4; ++r) {
      const float iv = 1.f / Lacc[qg][r];
      const size_t trow = (size_t)(qt * 256 + w * 32 + qg * 16 + quad * 4 + r);
      float* op = out + ((size_t)b * 2048 + trow) * 1024 + h * 64 + lq;
#pragma unroll
      for (int dg = 0; dg < 4; ++dg) op[dg * 16] = O[qg][dg][r] * iv;
    }
  }
}

extern "C" void kernel_launch(void* const* d_in, const int* in_sizes, int n_in,
                              void* d_out, int out_size, void* d_ws, size_t ws_size,
                              hipStream_t stream) {
  (void)in_sizes; (void)n_in; (void)out_size; (void)ws_size;
  const float* x = (const float*)d_in[0];
  const float* Wq = (const float*)d_in[1];
  const float* Wk = (const float*)d_in[2];
  const float* Wv = (const float*)d_in[3];
  const float* wip = (const float*)d_in[4];
  float* out = (float*)d_out;

  u16* xb = (u16*)d_ws;
  u16* wb = xb + 8388608;
  u16* qb = wb + 3145728;
  u16* kb = qb + 8388608;
  u16* vb = kb + 8388608;   // holds V^T [B][H][64][2048]

  cvt_all<<<11264, 256, 0, stream>>>(x, Wq, Wk, Wv, xb, wb);
  qkv_gemm<<<dim3(64, 8, 3), 256, 0, stream>>>(xb, wb, qb);
  palace_attn<<<dim3(64, 8, 1), 512, 0, stream>>>(qb, kb, vb, out, wip);
}

// Round 12
// 212.062 us; speedup vs baseline: 1.0753x; 1.0012x over previous
//
#include <hip/hip_runtime.h>

typedef unsigned short u16;
typedef unsigned int u32;
typedef short bf16x8 __attribute__((ext_vector_type(8)));
typedef float f32x4 __attribute__((ext_vector_type(4)));
typedef u32 u32x4 __attribute__((ext_vector_type(4)));

#define AS_GLOBAL __attribute__((address_space(1)))
#define AS_LDS __attribute__((address_space(3)))

__device__ __forceinline__ void async16(const void* g, void* l) {
  __builtin_amdgcn_global_load_lds((const AS_GLOBAL u32*)g, (AS_LDS u32*)l, 16, 0, 0);
}

__device__ __forceinline__ u16 f2bf(float f) {
  u32 u = __builtin_bit_cast(u32, f);
  u += 0x7FFFu + ((u >> 16) & 1u);   // RNE
  return (u16)(u >> 16);
}

__device__ __forceinline__ u32 pk2bf(float lo, float hi) {
  return __builtin_amdgcn_perm(__builtin_bit_cast(u32, hi),
                               __builtin_bit_cast(u32, lo), 0x07060302u);
}

__device__ __forceinline__ float fexp2(float x) {
#if __has_builtin(__builtin_amdgcn_exp2f)
  return __builtin_amdgcn_exp2f(x);
#else
  return exp2f(x);
#endif
}

// ---------------- Pass A: all four f32 -> bf16 converts in one launch ----------------
__global__ __launch_bounds__(256) void cvt_all(const float* __restrict__ x,
                                               const float* __restrict__ wq,
                                               const float* __restrict__ wk,
                                               const float* __restrict__ wv,
                                               u16* __restrict__ xb,
                                               u16* __restrict__ wb) {
  const int blk = blockIdx.x;
  const float* src;
  u16* dst;
  int i;
  if (blk < 8192) {
    src = x; dst = xb; i = blk * 256 + threadIdx.x;
  } else if (blk < 9216) {
    src = wq; dst = wb; i = (blk - 8192) * 256 + threadIdx.x;
  } else if (blk < 10240) {
    src = wk; dst = wb + 1048576; i = (blk - 9216) * 256 + threadIdx.x;
  } else {
    src = wv; dst = wb + 2097152; i = (blk - 10240) * 256 + threadIdx.x;
  }
  float4 f = reinterpret_cast<const float4*>(src)[i];
  ushort4 o;
  o.x = f2bf(f.x); o.y = f2bf(f.y); o.z = f2bf(f.z); o.w = f2bf(f.w);
  reinterpret_cast<ushort4*>(dst)[i] = o;
}

// ---------------- Pass B: QKV projection GEMM (C = X * W^T) ----------------
// Round-12 experiment (qkv): 8 WAVES/BLOCK (512 thr), per-wave 64x32 output
// (2 wave-rows x 4 wave-cols over the 128x128 tile). Per-CU MFMA/DMA totals
// unchanged; waves/CU 8 -> 16 (occupancy lever that won on attn in r8).
// Per-wave LDS reads 16 -> 12 per 16 MFMA (+50% per-CU, affordable at ~20%
// LDS load). K-loop otherwise r7-proven: BK=64, dbuf, one __syncthreads per
// k-tile, conflict-free chunk-XOR swizzle. Wide-store epilogue re-derived
// for 64x32 wave tiles: stage via LDS, 4 x global_store_dwordx4 per thread.
// grid: x = m-tile (64), y = n-tile (8), z = matrix (3)
// z=0 (Q), z=1 (K): out [B][H][T][64]; z=2 (V): out TRANSPOSED [B][H][64][T]
__global__ __launch_bounds__(512, 4) void qkv_gemm(const u16* __restrict__ X,
                                                   const u16* __restrict__ W,
                                                   u16* __restrict__ O) {
  const int z = blockIdx.z;
  const u16* Wz = W + (size_t)z * (1024 * 1024);
  u16* Oz = O + (size_t)z * (8192 * 1024);

  // unified 64KB: SMEM[0..1] = A dbuf, SMEM[2..3] = B dbuf; epilogue reuses
  // flat region: wave w gets 2560 u16 at sm + w*2560 (needs 2304).
  __shared__ __align__(16) u16 SMEM[4][8192];

  const int t = threadIdx.x;
  const int lane = t & 63, w = t >> 6, quad = lane >> 4, lq = lane & 15;
  const int wm = (w >> 2) * 64, wn = (w & 3) * 32;
  const int sw = lq & 7;
  const size_t m0 = (size_t)blockIdx.x * 128;
  const int n0 = blockIdx.y * 128;

  // staging source offsets (u16 units): slot -> (row, pre-swizzled chunk);
  // 512 threads x 2 slots cover one 128x64 panel (1024 16B chunks)
  int off[2];
#pragma unroll
  for (int j = 0; j < 2; ++j) {
    const int s = j * 512 + t, row = s >> 3, c = (s & 7) ^ (row & 7);
    off[j] = row * 1024 + c * 8;
  }
  const u16* gA = X + m0 * 1024;
  const u16* gB = Wz + (size_t)n0 * 1024;

  f32x4 acc[4][2];
#pragma unroll
  for (int i = 0; i < 4; ++i)
#pragma unroll
    for (int j = 0; j < 2; ++j) acc[i][j] = f32x4{0.f, 0.f, 0.f, 0.f};

  // 4 gload_lds(16B)/thread stages one 128x64 A panel + 128x64 B panel
  auto stage = [&](int kt, int nb) {
    const u16* ga = gA + kt * 64;
    const u16* gb = gB + kt * 64;
#pragma unroll
    for (int j = 0; j < 2; ++j)
      async16(ga + off[j], &SMEM[nb][(j * 512 + t) * 8]);
#pragma unroll
    for (int j = 0; j < 2; ++j)
      async16(gb + off[j], &SMEM[2 + nb][(j * 512 + t) * 8]);
  };

  // prologue: stage tile 0 into buffer 0
  stage(0, 0);

  for (int kt = 0; kt < 16; ++kt) {
    const int cur = kt & 1;
    __syncthreads();                    // tile kt resident; buf[cur^1] free
    if (kt < 15) stage(kt + 1, cur ^ 1);

    bf16x8 Af[4][2], Bf[2][2];
#pragma unroll
    for (int ks = 0; ks < 2; ++ks) {
#pragma unroll
      for (int i = 0; i < 4; ++i)
        Af[i][ks] = *reinterpret_cast<const bf16x8*>(
            &SMEM[cur][(wm + i * 16 + lq) * 64 + ((ks * 4 + quad) ^ sw) * 8]);
#pragma unroll
      for (int j = 0; j < 2; ++j)
        Bf[j][ks] = *reinterpret_cast<const bf16x8*>(
            &SMEM[2 + cur][(wn + j * 16 + lq) * 64 + ((ks * 4 + quad) ^ sw) * 8]);
    }
#pragma unroll
    for (int i = 0; i < 4; ++i)
#pragma unroll
      for (int j = 0; j < 2; ++j) {
        acc[i][j] = __builtin_amdgcn_mfma_f32_16x16x32_bf16(Af[i][0], Bf[j][0], acc[i][j], 0, 0, 0);
        acc[i][j] = __builtin_amdgcn_mfma_f32_16x16x32_bf16(Af[i][1], Bf[j][1], acc[i][j], 0, 0, 0);
      }
  }

  // ---- wide-store epilogue (per-wave 64x32 tile) ----
  __syncthreads();                      // all LDS reads of the main loop done
  u16* ep = &SMEM[0][0] + w * 2560;     // wave-private region
  const size_t ms = m0 + wm;
  const size_t bb = ms >> 11, tt0 = ms & 2047;
  const int hh = (n0 + wn) >> 6, d0 = (n0 + wn) & 63;   // d0 in {0,32}
  if (z != 2) {
    // LDS layout [64 rows(m)][36]: col = local n (0..31)
#pragma unroll
    for (int i = 0; i < 4; ++i)
#pragma unroll
      for (int j = 0; j < 2; ++j)
#pragma unroll
        for (int r = 0; r < 4; ++r)
          ep[(i * 16 + quad * 4 + r) * 36 + j * 16 + lq] = f2bf(acc[i][j][r]);
    asm volatile("s_waitcnt lgkmcnt(0)" ::: "memory");
    // 64 rows x 64B (4 chunks); 4 stores/thread, rows 16-granular
    u16* gbase = Oz + ((bb * 16 + hh) * 2048 + tt0) * 64 + d0;
#pragma unroll
    for (int kq = 0; kq < 4; ++kq) {
      const int row = kq * 16 + (lane >> 2), c = lane & 3;
      bf16x8 v = *reinterpret_cast<const bf16x8*>(&ep[row * 36 + c * 8]);
      *reinterpret_cast<bf16x8*>(&gbase[(size_t)row * 64 + c * 8]) = v;
    }
  } else {
    // transposed: LDS layout [32 rows(d)][72]: col = local m (0..63)
#pragma unroll
    for (int i = 0; i < 4; ++i)
#pragma unroll
      for (int j = 0; j < 2; ++j)
#pragma unroll
        for (int r = 0; r < 4; ++r)
          ep[(j * 16 + lq) * 72 + i * 16 + quad * 4 + r] = f2bf(acc[i][j][r]);
    asm volatile("s_waitcnt lgkmcnt(0)" ::: "memory");
    // 32 rows (d) x 128B (8 chunks); 4 stores/thread
    u16* gbase = Oz + ((size_t)(bb * 16 + hh) * 64 + d0) * 2048 + tt0;
#pragma unroll
    for (int kq = 0; kq < 4; ++kq) {
      const int row = kq * 8 + (lane >> 3), c = lane & 7;
      bf16x8 v = *reinterpret_cast<const bf16x8*>(&ep[row * 72 + c * 8]);
      *reinterpret_cast<bf16x8*>(&gbase[(size_t)row * 2048 + c * 8]) = v;
    }
  }
}

// ---------------- Pass C: flash attention, S^T-form, full-rate 16x16x32 PV ----------------
// Round-12 experiment (attn): KVBLK 64 -> 128. Doubles the independent work
// between barriers (4 key-halves/iter -> more ILP for the latency-bound
// chain), halves barrier+drain events (32 -> 16 kt). LDS 64 KB/block ->
// still 2 blocks/CU. Keeps r11's proven stagger (h0 = w&3 over 4 halves)
// and setprio. Swizzle algebra extends: staging XOR s(row) =
// (row&3)|(((row>>3)&1)<<2) matches the read XOR for K rows 0..127
// (krow&3 = lq&3, krow bit3 = lq bit2) and V rows (row = dg*16+lq).
// Palace mask: key%64 block = (half&1)*4 + quad (uniform over a lane's 8
// keys); q-slot = (w&1)*4 + qg*2 + lq3. Everything else unchanged.
__global__ __launch_bounds__(512, 4) void palace_attn(const u16* __restrict__ Q,
                                                      const u16* __restrict__ K,
                                                      const u16* __restrict__ Vt,
                                                      float* __restrict__ out,
                                                      const float* __restrict__ wptr) {
  const int bh = blockIdx.x, qt = blockIdx.y;
  const int h = bh & 15, b = bh >> 4;
  const size_t base = (size_t)bh * (2048 * 64);

  __shared__ __align__(16) u16 Ks[2][128 * 64];  // [key][d], swizzled 16B chunks
  __shared__ __align__(16) u16 Vs[2][64 * 128];  // [d][key], swizzled 16B chunks

  const int t = threadIdx.x;
  const int w = t >> 6, lane = t & 63, quad = lane >> 4, lq = lane & 15;
  const int lq3 = lq >> 3;
  const int swk = (lq & 3) | (((lq >> 2) & 1) << 2);  // s(row) for permuted K rows
  const int swv = (lq & 3) | (lq3 << 2);              // s(d) for V rows d=dg*16+lq
  const float sig = 1.f / (1.f + __expf(-wptr[0]));
  const float Ci = 0.125f * 1.44269504f;   // intra coeff (scale * log2 e)
  const float Co = Ci * sig;               // inter coeff
  const float MC = 14.4269504f;            // fixed softmax offset: 10 * log2 e

  // palace mask: q-slot = (w&1)*4 + qg*2 + lq3; key-slot = (half&1)*4 + quad
  const int qs0 = (w & 1) * 4;
  float cft[2][2];
#pragma unroll
  for (int hb = 0; hb < 2; ++hb)
#pragma unroll
    for (int qg = 0; qg < 2; ++qg)
      cft[hb][qg] = (hb * 4 + quad == qs0 + qg * 2 + lq3) ? Ci : Co;

  // Q B-frags (16x16x32): B[k=d][n=q], q = qt*256 + w*32 + qg*16 + lq
  bf16x8 qf[2][2];
#pragma unroll
  for (int qg = 0; qg < 2; ++qg)
#pragma unroll
    for (int kc = 0; kc < 2; ++kc)
      qf[qg][kc] = *reinterpret_cast<const bf16x8*>(
          Q + base + (size_t)(qt * 256 + w * 32 + qg * 16 + lq) * 64 + kc * 32 + quad * 8);

  // staging offsets: K tile [128][64] = 1024 chunks, slots t and 512+t:
  //   row = s>>3 (0..127), source chunk = (s&7) ^ s(row)
  // V tile [64][128] = 1024 chunks: row = s>>4 (0..63), chunk = (s&15)^s(row)
  int ko[2], vo[2];
#pragma unroll
  for (int r = 0; r < 2; ++r) {
    const int s = r * 512 + t;
    const int rk = s >> 3;
    const int srk = (rk & 3) | (((rk >> 3) & 1) << 2);
    ko[r] = rk * 64 + ((s & 7) ^ srk) * 8;          // K: [key][64] in global
    const int rv = s >> 4;
    const int srv = (rv & 3) | (((rv >> 3) & 1) << 2);
    vo[r] = rv * 2048 + ((s & 15) ^ srv) * 8;       // Vt: [d][2048] in global
  }

  f32x4 O[2][4];
  f32x4 Lacc[2];
#pragma unroll
  for (int qg = 0; qg < 2; ++qg) {
    Lacc[qg] = f32x4{0.f, 0.f, 0.f, 0.f};
#pragma unroll
    for (int dg = 0; dg < 4; ++dg) O[qg][dg] = f32x4{0.f, 0.f, 0.f, 0.f};
  }

  const short oneb = (short)0x3F80;  // bf16 1.0
  const bf16x8 ones8 = {oneb, oneb, oneb, oneb, oneb, oneb, oneb, oneb};

  const int h0 = w & 3;  // wave-staggered half order over 4 halves

  // stage K/V tile kt into buffer nb (2 K + 2 V loads per thread)
  auto stage = [&](int kt, int nb) {
    const u16* kgp = K + base + (size_t)kt * 8192;   // 128 keys x 64 d
    const u16* vgp = Vt + base + (size_t)kt * 128;   // cols kt*128..+127
#pragma unroll
    for (int r = 0; r < 2; ++r) {
      async16(kgp + ko[r], &Ks[nb][(r * 512 + t) * 8]);
      async16(vgp + vo[r], &Vs[nb][(r * 512 + t) * 8]);
    }
  };

  // prologue: stage tile 0 into buffer 0
  stage(0, 0);

  for (int kt = 0; kt < 16; ++kt) {
    const int cur = kt & 1;
    __syncthreads();  // drains DMA into buf[cur]; prior reads of buf[cur^1] done
    if (kt < 15) stage(kt + 1, cur ^ 1);

#pragma unroll
    for (int hx = 0; hx < 4; ++hx) {
      const int half = hx ^ h0;  // waves process halves in different orders
      const int hb = half & 1;   // key%64 block base
      // permuted K rows: key = half*32 + (lq>>2)*8 + kg2*4 + (lq&3)
      const int rb = half * 32 + ((lq >> 2) << 3) + (lq & 3);
      bf16x8 kf[2][2];
#pragma unroll
      for (int kg2 = 0; kg2 < 2; ++kg2) {
        const int krow = rb + kg2 * 4;
        kf[kg2][0] = *reinterpret_cast<const bf16x8*>(
            &Ks[cur][krow * 64 + (quad ^ swk) * 8]);          // d chunk = quad
        kf[kg2][1] = *reinterpret_cast<const bf16x8*>(
            &Ks[cur][krow * 64 + ((quad + 4) ^ swk) * 8]);    // d chunk = quad+4
      }

      // V B-frags: B[k=key][n=d], keys half*32+quad*8..+7 contiguous;
      // V row = dg*16+lq (128 u16 wide -> 16 chunks), chunk = half*4+quad
      bf16x8 vbf[4];
#pragma unroll
      for (int dg = 0; dg < 4; ++dg)
        vbf[dg] = *reinterpret_cast<const bf16x8*>(
            &Vs[cur][(dg * 16 + lq) * 128 + ((half * 4 + quad) ^ swv) * 8]);

#pragma unroll
      for (int qg = 0; qg < 2; ++qg) {
        // S^T[key][q] for the 32-key half: two sub-MFMAs x two d-chunks
        f32x4 z0 = {0.f, 0.f, 0.f, 0.f}, z1 = {0.f, 0.f, 0.f, 0.f};
        __builtin_amdgcn_s_setprio(1);
        z0 = __builtin_amdgcn_mfma_f32_16x16x32_bf16(kf[0][0], qf[qg][0], z0, 0, 0, 0);
        z0 = __builtin_amdgcn_mfma_f32_16x16x32_bf16(kf[0][1], qf[qg][1], z0, 0, 0, 0);
        z1 = __builtin_amdgcn_mfma_f32_16x16x32_bf16(kf[1][0], qf[qg][0], z1, 0, 0, 0);
        z1 = __builtin_amdgcn_mfma_f32_16x16x32_bf16(kf[1][1], qf[qg][1], z1, 0, 0, 0);
        __builtin_amdgcn_s_setprio(0);

        const float cf = cft[hb][qg];
        const float p0 = fexp2(__builtin_fmaf(z0[0], cf, -MC));
        const float p1 = fexp2(__builtin_fmaf(z0[1], cf, -MC));
        const float p2 = fexp2(__builtin_fmaf(z0[2], cf, -MC));
        const float p3 = fexp2(__builtin_fmaf(z0[3], cf, -MC));
        const float p4 = fexp2(__builtin_fmaf(z1[0], cf, -MC));
        const float p5 = fexp2(__builtin_fmaf(z1[1], cf, -MC));
        const float p6 = fexp2(__builtin_fmaf(z1[2], cf, -MC));
        const float p7 = fexp2(__builtin_fmaf(z1[3], cf, -MC));

        u32x4 pk;
        pk.x = pk2bf(p0, p1);
        pk.y = pk2bf(p2, p3);
        pk.z = pk2bf(p4, p5);
        pk.w = pk2bf(p6, p7);
        const bf16x8 pa = __builtin_bit_cast(bf16x8, pk);

        // softmax denominator: C reg r = sum_k P[q=qg*16+quad*4+r][k]
        __builtin_amdgcn_s_setprio(1);
        Lacc[qg] = __builtin_amdgcn_mfma_f32_16x16x32_bf16(pa, ones8, Lacc[qg], 0, 0, 0);
#pragma unroll
        for (int dg = 0; dg < 4; ++dg)
          O[qg][dg] = __builtin_amdgcn_mfma_f32_16x16x32_bf16(pa, vbf[dg], O[qg][dg], 0, 0, 0);
        __builtin_amdgcn_s_setprio(0);
      }
    }
  }

  // epilogue: O C-layout: q = qg*16+quad*4+r (row), d = dg*16+lq (col);
  // Lacc has the matching row layout -- no cross-lane reduce needed.
#pragma unroll
  for (int qg = 0; qg < 2; ++qg) {
#pragma unroll
    for (int r = 0; r < 4; ++r) {
      const float iv = 1.f / Lacc[qg][r];
      const size_t trow = (size_t)(qt * 256 + w * 32 + qg * 16 + quad * 4 + r);
      float* op = out + ((size_t)b * 2048 + trow) * 1024 + h * 64 + lq;
#pragma unroll
      for (int dg = 0; dg < 4; ++dg) op[dg * 16] = O[qg][dg][r] * iv;
    }
  }
}

extern "C" void kernel_launch(void* const* d_in, const int* in_sizes, int n_in,
                              void* d_out, int out_size, void* d_ws, size_t ws_size,
                              hipStream_t stream) {
  (void)in_sizes; (void)n_in; (void)out_size; (void)ws_size;
  const float* x = (const float*)d_in[0];
  const float* Wq = (const float*)d_in[1];
  const float* Wk = (const float*)d_in[2];
  const float* Wv = (const float*)d_in[3];
  const float* wip = (const float*)d_in[4];
  float* out = (float*)d_out;

  u16* xb = (u16*)d_ws;
  u16* wb = xb + 8388608;
  u16* qb = wb + 3145728;
  u16* kb = qb + 8388608;
  u16* vb = kb + 8388608;   // holds V^T [B][H][64][2048]

  cvt_all<<<11264, 256, 0, stream>>>(x, Wq, Wk, Wv, xb, wb);
  qkv_gemm<<<dim3(64, 8, 3), 512, 0, stream>>>(xb, wb, qb);
  palace_attn<<<dim3(64, 8, 1), 512, 0, stream>>>(qb, kb, vb, out, wip);
}